// Round 3
// baseline (36849.820 us; speedup 1.0000x reference)
//
#include <hip/hip_runtime.h>
#include <hip/hip_cooperative_groups.h>
#include <cmath>

namespace cg = cooperative_groups;

// Model dims
#define TSTEPS 512
#define BB     128      // batch
#define HD     1024     // hidden
#define GD     4096     // 4*H
#define VD     128      // vocab
#define ED     128      // char emb
#define IE     32       // img emb
#define CD     160      // IE+ED

// ---------------- Fold kernels (run once per launch, trivial cost) ----------

// Wc[g][c] = sum_e W_ih[g][e] * W_proj[e][c];  gb[g] = b_ih+b_hh+W_ih@b_proj
__global__ void fold_wc_kernel(const float* __restrict__ W_ih,
                               const float* __restrict__ W_proj,
                               const float* __restrict__ b_proj,
                               const float* __restrict__ b_ih,
                               const float* __restrict__ b_hh,
                               float* __restrict__ Wc,
                               float* __restrict__ gb) {
    int idx = blockIdx.x * 256 + threadIdx.x;
    if (idx < GD * CD) {
        int g = idx / CD, c = idx - g * CD;
        const float* wr = W_ih + g * ED;
        float s = 0.f;
        #pragma unroll 8
        for (int e = 0; e < ED; ++e) s = fmaf(wr[e], W_proj[e * CD + c], s);
        Wc[idx] = s;
    }
    if (idx < GD) {
        const float* wr = W_ih + idx * ED;
        float s = b_ih[idx] + b_hh[idx];
        #pragma unroll 8
        for (int e = 0; e < ED; ++e) s = fmaf(wr[e], b_proj[e], s);
        gb[idx] = s;
    }
}

// Gimgb[b][g] = gb[g] + sum_{k<32} emb_img[img[b]][k] * Wc[g][k]
__global__ void fold_gimg_kernel(const float* __restrict__ emb_img,
                                 const int* __restrict__ input_img,
                                 const float* __restrict__ Wc,
                                 const float* __restrict__ gb,
                                 float* __restrict__ Gimgb) {
    int idx = blockIdx.x * 256 + threadIdx.x;   // BB*GD
    int b = idx >> 12, g = idx & (GD - 1);
    const float* e = emb_img + (size_t)input_img[b] * IE;
    const float* w = Wc + g * CD;
    float s = gb[g];
    #pragma unroll
    for (int k = 0; k < IE; ++k) s = fmaf(e[k], w[k], s);
    Gimgb[idx] = s;
}

// Gtok[v][g] = sum_{k<128} emb_char[v][k] * Wc[g][32+k]
__global__ void fold_gtok_kernel(const float* __restrict__ emb_char,
                                 const float* __restrict__ Wc,
                                 float* __restrict__ Gtok) {
    int idx = blockIdx.x * 256 + threadIdx.x;   // VD*GD
    int v = idx >> 12, g = idx & (GD - 1);
    const float* e = emb_char + v * ED;
    const float* w = Wc + g * CD + IE;
    float s = 0.f;
    #pragma unroll 8
    for (int k = 0; k < ED; ++k) s = fmaf(e[k], w[k], s);
    Gtok[idx] = s;
}

__global__ void hbuf_init_kernel(float* __restrict__ hbuf) {
    int idx = blockIdx.x * 256 + threadIdx.x;   // 2*BB*HD = 262144
    hbuf[idx] = 0.f;
}

// ---------------- Persistent-register cooperative LSTM + fused logits ------
// grid = 256 blocks x 512 threads (1 block/CU, 8 waves/CU, 256 VGPR/thread).
// Block: bgrp = bid>>6 (32 batch rows), jgrp = bid&63 (16 columns).
// Wave w: columns jgrp*16 + w*2 + {0,1} (lane half). lk = lane&31 is a 32-way
// k-split (k in [lk*32, lk*32+32)). Each thread PERSISTENTLY holds its
// column's 4 gate-rows x 32-k weight chunk in 128 VGPRs -> zero weight
// memory traffic in the recurrence. Lane lk owns batch row bgrp*32+lk for
// activation/c-state of its half's column.
// h staged per 16-row half into 64KB LDS with XOR swizzle c^((c>>3)&7) to
// avoid 128B-stride bank-quad collisions on the gate-FMA reads.
__global__ __launch_bounds__(512, 2) void lstm_fused(
    const float* __restrict__ W_hh,    // [4096][1024]
    const float* __restrict__ Gimgb,   // [128][4096]
    const float* __restrict__ Gtok,    // [128][4096]
    const float* __restrict__ Wfc,     // [128][1024]
    const float* __restrict__ bfc,     // [128]
    const int*   __restrict__ x,       // [128][512]
    const int*   __restrict__ label,   // [128][512]
    float*       __restrict__ hbuf,    // [2][128][1024]
    float*       __restrict__ logits)  // [128][512][128]
{
    __shared__ float4 hlds4[16 * 256];  // 64 KiB: 16 h rows (swizzled)
    cg::grid_group grid = cg::this_grid();

    const int tid  = threadIdx.x;
    const int bid  = blockIdx.x;
    const int bgrp = bid >> 6;          // 0..3
    const int jgrp = bid & 63;          // 0..63
    const int w    = tid >> 6;          // 0..7
    const int lane = tid & 63;
    const int half = lane >> 5;
    const int lk   = lane & 31;
    const int col  = jgrp * 16 + w * 2 + half;   // 0..1023
    const int b_glob = bgrp * 32 + lk;           // owned batch row

    // logits mapping: 32 dots per half (16 rows x 2 vocab), 16 threads/dot
    const int dotid  = tid >> 4;        // 0..31
    const int kc     = tid & 15;
    const int lb_loc = dotid >> 1;      // 0..15
    const int vv     = jgrp * 2 + (dotid & 1);   // 0..127
    const float bfcv = bfc[vv];

    // ---- persistent weight load (once) ----
    const float4* __restrict__ Whh4 = reinterpret_cast<const float4*>(W_hh);
    float4 wreg[4][8];
    #pragma unroll
    for (int g = 0; g < 4; ++g)
        #pragma unroll
        for (int i = 0; i < 8; ++i)
            wreg[g][i] = Whh4[(size_t)(g * HD + col) * 256 + lk * 8 + i];

    const float4* __restrict__ Wfc4 = reinterpret_cast<const float4*>(Wfc);

    const int bit0 = lk & 1, bit1 = (lk >> 1) & 1, bit2 = (lk >> 2) & 1;

    float c_reg = 0.f;
    int cur = 0;

    for (int t = 0; t <= TSTEPS; ++t) {
        const bool last = (t == TSTEPS);

        // gate-bias gathers issued early; latency hides under stage+FMA
        float ab0 = 0.f, ab1 = 0.f, ab2 = 0.f, ab3 = 0.f;
        if (!last) {
            const int tok = (t == 0) ? x[b_glob * TSTEPS]
                                     : label[b_glob * TSTEPS + t - 1];
            const float* gi = Gimgb + (size_t)b_glob * GD + col;
            const float* gt = Gtok  + (size_t)tok   * GD + col;
            ab0 = gi[0]    + gt[0];
            ab1 = gi[1024] + gt[1024];
            ab2 = gi[2048] + gt[2048];
            ab3 = gi[3072] + gt[3072];
        }
        float aval0 = 0.f, aval1 = 0.f, aval2 = 0.f, aval3 = 0.f;

        #pragma unroll
        for (int hh = 0; hh < 2; ++hh) {
            // ---- stage 16 h rows into LDS (swizzled) ----
            {
                const float4* src = reinterpret_cast<const float4*>(
                    hbuf + (size_t)cur * (BB * HD))
                    + (size_t)(bgrp * 32 + hh * 16) * 256;
                #pragma unroll
                for (int jj = 0; jj < 8; ++jj) {
                    int idx  = tid + jj * 512;
                    int c    = idx & 255;
                    int rowl = idx >> 8;
                    hlds4[rowl * 256 + (c ^ ((c >> 3) & 7))] = src[idx];
                }
            }
            __syncthreads();

            // ---- logits for step t-1 over these 16 rows ----
            if (t > 0) {
                float s = 0.f;
                #pragma unroll
                for (int m = 0; m < 16; ++m) {
                    int c = m * 16 + kc;
                    float4 h4 = hlds4[lb_loc * 256 + (c ^ ((c >> 3) & 7))];
                    float4 w4 = Wfc4[(size_t)vv * 256 + c];
                    s = fmaf(h4.x, w4.x, fmaf(h4.y, w4.y,
                        fmaf(h4.z, w4.z, fmaf(h4.w, w4.w, s))));
                }
                s += __shfl_xor(s, 1); s += __shfl_xor(s, 2);
                s += __shfl_xor(s, 4); s += __shfl_xor(s, 8);
                if (kc == 0)
                    logits[((size_t)(bgrp * 32 + hh * 16 + lb_loc) * TSTEPS
                            + (t - 1)) * VD + vv] = s + bfcv;
            }

            // ---- gate FMA: 2 passes of 8 rows ----
            if (!last) {
                #pragma unroll
                for (int p = 0; p < 2; ++p) {
                    float acc[4][8];
                    #pragma unroll
                    for (int g = 0; g < 4; ++g)
                        #pragma unroll
                        for (int b = 0; b < 8; ++b) acc[g][b] = 0.f;

                    #pragma unroll
                    for (int b = 0; b < 8; ++b) {
                        const int rowl = p * 8 + b;
                        float4 h4[8];
                        #pragma unroll
                        for (int i = 0; i < 8; ++i)
                            h4[i] = hlds4[rowl * 256 + ((lk * 8 + i) ^ (lk & 7))];
                        #pragma unroll
                        for (int g = 0; g < 4; ++g)
                            #pragma unroll
                            for (int i = 0; i < 8; ++i)
                                acc[g][b] = fmaf(wreg[g][i].x, h4[i].x,
                                             fmaf(wreg[g][i].y, h4[i].y,
                                              fmaf(wreg[g][i].z, h4[i].z,
                                               fmaf(wreg[g][i].w, h4[i].w,
                                                    acc[g][b]))));
                    }

                    // value-halving butterfly: 8 partials -> owner lanes.
                    // Owner of batch row b is lane b; value routes toward
                    // the lane whose bits match b's bits at each stage.
                    const bool own = ((lk >> 3) == hh * 2 + p);
                    #pragma unroll
                    for (int g = 0; g < 4; ++g) {
                        float s0 = bit0 ? acc[g][0] : acc[g][1];
                        float s1 = bit0 ? acc[g][2] : acc[g][3];
                        float s2 = bit0 ? acc[g][4] : acc[g][5];
                        float s3 = bit0 ? acc[g][6] : acc[g][7];
                        float p0 = (bit0 ? acc[g][1] : acc[g][0]) + __shfl_xor(s0, 1);
                        float p1 = (bit0 ? acc[g][3] : acc[g][2]) + __shfl_xor(s1, 1);
                        float p2 = (bit0 ? acc[g][5] : acc[g][4]) + __shfl_xor(s2, 1);
                        float p3 = (bit0 ? acc[g][7] : acc[g][6]) + __shfl_xor(s3, 1);
                        float q0 = (bit1 ? p1 : p0) + __shfl_xor(bit1 ? p0 : p1, 2);
                        float q1 = (bit1 ? p3 : p2) + __shfl_xor(bit1 ? p2 : p3, 2);
                        float u  = (bit2 ? q1 : q0) + __shfl_xor(bit2 ? q0 : q1, 4);
                        u += __shfl_xor(u, 8);
                        u += __shfl_xor(u, 16);
                        if (g == 0)      aval0 = own ? u : aval0;
                        else if (g == 1) aval1 = own ? u : aval1;
                        else if (g == 2) aval2 = own ? u : aval2;
                        else             aval3 = own ? u : aval3;
                    }
                }
            }
            __syncthreads();
        }

        if (!last) {
            // torch gate order: i, f, g, o
            float a0 = aval0 + ab0, a1 = aval1 + ab1;
            float a2 = aval2 + ab2, a3 = aval3 + ab3;
            float ig = 1.f / (1.f + expf(-a0));
            float fg = 1.f / (1.f + expf(-a1));
            float gg = tanhf(a2);
            float og = 1.f / (1.f + expf(-a3));
            c_reg = fmaf(fg, c_reg, ig * gg);
            float hnew = og * tanhf(c_reg);
            hbuf[(size_t)(cur ^ 1) * (BB * HD) + (size_t)b_glob * HD + col] = hnew;
            grid.sync();
            cur ^= 1;
        }
    }
}

// ---------------- argmax (first-occurrence tie-break, preds as float) -------
__global__ void argmax_kernel(const float* __restrict__ logits,
                              float* __restrict__ preds) {
    int row = blockIdx.x * 4 + (threadIdx.x >> 6);   // 65536 rows
    int lane = threadIdx.x & 63;
    const float* r = logits + (size_t)row * VD;
    float v0 = r[lane * 2], v1 = r[lane * 2 + 1];
    float bv; int bi;
    if (v1 > v0) { bv = v1; bi = lane * 2 + 1; } else { bv = v0; bi = lane * 2; }
    #pragma unroll
    for (int d = 32; d >= 1; d >>= 1) {
        float ov = __shfl_down(bv, d);
        int   oi = __shfl_down(bi, d);
        if (ov > bv || (ov == bv && oi < bi)) { bv = ov; bi = oi; }
    }
    if (lane == 0) preds[row] = (float)bi;
}

// ---------------- launch ----------------------------------------------------
extern "C" void kernel_launch(void* const* d_in, const int* in_sizes, int n_in,
                              void* d_out, int out_size, void* d_ws, size_t ws_size,
                              hipStream_t stream) {
    const int*   input_img = (const int*)  d_in[0];
    const int*   x         = (const int*)  d_in[1];
    const int*   label     = (const int*)  d_in[2];
    const float* emb_img   = (const float*)d_in[3];
    const float* emb_char  = (const float*)d_in[4];
    const float* W_proj    = (const float*)d_in[5];
    const float* b_proj    = (const float*)d_in[6];
    const float* W_ih      = (const float*)d_in[7];
    const float* W_hh      = (const float*)d_in[8];
    const float* b_ih      = (const float*)d_in[9];
    const float* b_hh      = (const float*)d_in[10];
    const float* W_fc      = (const float*)d_in[11];
    const float* b_fc      = (const float*)d_in[12];

    float* ws     = (float*)d_ws;
    float* Wc     = ws;                          // 4096*160
    float* gb     = Wc + (size_t)GD * CD;        // 4096
    float* Gimgb  = gb + GD;                     // 128*4096
    float* Gtok   = Gimgb + (size_t)BB * GD;     // 128*4096
    float* hbuf   = Gtok + (size_t)VD * GD;      // 2*128*1024

    float* logits = (float*)d_out;               // 128*512*128
    float* preds  = logits + (size_t)BB * TSTEPS * VD;

    fold_wc_kernel  <<<(GD * CD + 255) / 256, 256, 0, stream>>>(W_ih, W_proj, b_proj, b_ih, b_hh, Wc, gb);
    fold_gimg_kernel<<<(BB * GD) / 256, 256, 0, stream>>>(emb_img, input_img, Wc, gb, Gimgb);
    fold_gtok_kernel<<<(VD * GD) / 256, 256, 0, stream>>>(emb_char, Wc, Gtok);
    hbuf_init_kernel<<<(2 * BB * HD) / 256, 256, 0, stream>>>(hbuf);

    void* args[] = { (void*)&W_hh, (void*)&Gimgb, (void*)&Gtok, (void*)&W_fc,
                     (void*)&b_fc, (void*)&x, (void*)&label, (void*)&hbuf, (void*)&logits };
    hipLaunchCooperativeKernel((void*)lstm_fused, dim3(256), dim3(512), args, 0, stream);

    argmax_kernel<<<(BB * TSTEPS) / 4, 256, 0, stream>>>(logits, preds);
}

// Round 4
// 31006.030 us; speedup vs baseline: 1.1885x; 1.1885x over previous
//
#include <hip/hip_runtime.h>
#include <hip/hip_cooperative_groups.h>
#include <cmath>

namespace cg = cooperative_groups;

// Model dims
#define TSTEPS 512
#define BB     128      // batch
#define HD     1024     // hidden
#define GD     4096     // 4*H
#define VD     128      // vocab
#define ED     128      // char emb
#define IE     32       // img emb
#define CD     160      // IE+ED

// ---------------- Fold kernels (run once per launch, trivial cost) ----------

// Wc[g][c] = sum_e W_ih[g][e] * W_proj[e][c];  gb[g] = b_ih+b_hh+W_ih@b_proj
__global__ void fold_wc_kernel(const float* __restrict__ W_ih,
                               const float* __restrict__ W_proj,
                               const float* __restrict__ b_proj,
                               const float* __restrict__ b_ih,
                               const float* __restrict__ b_hh,
                               float* __restrict__ Wc,
                               float* __restrict__ gb) {
    int idx = blockIdx.x * 256 + threadIdx.x;
    if (idx < GD * CD) {
        int g = idx / CD, c = idx - g * CD;
        const float* wr = W_ih + g * ED;
        float s = 0.f;
        #pragma unroll 8
        for (int e = 0; e < ED; ++e) s = fmaf(wr[e], W_proj[e * CD + c], s);
        Wc[idx] = s;
    }
    if (idx < GD) {
        const float* wr = W_ih + idx * ED;
        float s = b_ih[idx] + b_hh[idx];
        #pragma unroll 8
        for (int e = 0; e < ED; ++e) s = fmaf(wr[e], b_proj[e], s);
        gb[idx] = s;
    }
}

// Gimgb[b][g] = gb[g] + sum_{k<32} emb_img[img[b]][k] * Wc[g][k]
__global__ void fold_gimg_kernel(const float* __restrict__ emb_img,
                                 const int* __restrict__ input_img,
                                 const float* __restrict__ Wc,
                                 const float* __restrict__ gb,
                                 float* __restrict__ Gimgb) {
    int idx = blockIdx.x * 256 + threadIdx.x;   // BB*GD
    int b = idx >> 12, g = idx & (GD - 1);
    const float* e = emb_img + (size_t)input_img[b] * IE;
    const float* w = Wc + g * CD;
    float s = gb[g];
    #pragma unroll
    for (int k = 0; k < IE; ++k) s = fmaf(e[k], w[k], s);
    Gimgb[idx] = s;
}

// Gtok[v][g] = sum_{k<128} emb_char[v][k] * Wc[g][32+k]
__global__ void fold_gtok_kernel(const float* __restrict__ emb_char,
                                 const float* __restrict__ Wc,
                                 float* __restrict__ Gtok) {
    int idx = blockIdx.x * 256 + threadIdx.x;   // VD*GD
    int v = idx >> 12, g = idx & (GD - 1);
    const float* e = emb_char + v * ED;
    const float* w = Wc + g * CD + IE;
    float s = 0.f;
    #pragma unroll 8
    for (int k = 0; k < ED; ++k) s = fmaf(e[k], w[k], s);
    Gtok[idx] = s;
}

__global__ void hbuf_init_kernel(float* __restrict__ hbuf) {
    int idx = blockIdx.x * 256 + threadIdx.x;   // 2*BB*HD = 262144
    hbuf[idx] = 0.f;
}

// ---------------- Persistent-register cooperative LSTM + fused logits ------
// grid = 256 blocks x 512 threads (1 block/CU, 8 waves/CU — grid-limited).
// Block: bgrp = bid>>7 (64 batch rows), jgrp = bid&127 (8 hidden cols).
// Wave w -> hidden col jgrp*8+w (all 4 gates). Lane L: interleaved 64-way
// k-split: lane L owns k in {256i+4L..256i+4L+3 : i=0..3} -> every LDS
// gate-read is lane-contiguous b128 (conflict-free). Weights: 4 gates x 4 f4
// = 64 VGPRs, persistent across all steps (zero weight traffic).
// Lane L owns batch row bgrp*64+L: after the 6-stage butterfly, pass
// (st,p)==L>>3 delivers row value v==L&7 exactly to its owner.
// h staged 16 rows/stage into 64KB LDS; per-row rotation (c+4r)&255 spreads
// the logits row-group reads across banks.
__global__ __launch_bounds__(512, 1) void lstm_fused(
    const float* __restrict__ W_hh,    // [4096][1024]
    const float* __restrict__ Gimgb,   // [128][4096]
    const float* __restrict__ Gtok,    // [128][4096]
    const float* __restrict__ Wfc,     // [128][1024]
    const float* __restrict__ bfc,     // [128]
    const int*   __restrict__ x,       // [128][512]
    const int*   __restrict__ label,   // [128][512]
    float*       __restrict__ hbuf,    // [2][128][1024]
    float*       __restrict__ logits)  // [128][512][128]
{
    __shared__ float4 hlds4[16 * 256];  // 64 KiB: 16 h rows (rotated layout)
    cg::grid_group grid = cg::this_grid();

    const int tid  = threadIdx.x;
    const int bid  = blockIdx.x;
    const int bgrp = bid >> 7;          // 0..1
    const int jgrp = bid & 127;         // 0..127
    const int w    = tid >> 6;          // 0..7
    const int L    = tid & 63;
    const int col  = jgrp * 8 + w;      // 0..1023
    const int row_own = bgrp * 64 + L;  // owned batch row
    const int pass_own = L >> 3;        // which (st*2+p) delivers my row
    // logits: vocab vv = jgrp; dot = row (16/stage), 32 threads/dot over k
    const int dotid = tid >> 5;         // 0..15 local row
    const int kc    = tid & 31;
    const float bfcv = bfc[jgrp];

    const float4* __restrict__ Whh4 = reinterpret_cast<const float4*>(W_hh);
    const float4* __restrict__ Wfc4 = reinterpret_cast<const float4*>(Wfc);

    // ---- persistent weight load (once): interleaved k-chunk of this col ----
    float4 wreg[4][4];
    #pragma unroll
    for (int g = 0; g < 4; ++g)
        #pragma unroll
        for (int i = 0; i < 4; ++i)
            wreg[g][i] = Whh4[(size_t)(g * HD + col) * 256 + i * 64 + L];

    const int bit0 = L & 1, bit1 = (L >> 1) & 1, bit2 = (L >> 2) & 1;

    float c_reg = 0.f;
    int cur = 0;

    for (int t = 0; t <= TSTEPS; ++t) {
        const bool last = (t == TSTEPS);

        // gate-bias gathers issued early; latency hides under stage+FMA
        float ab0 = 0.f, ab1 = 0.f, ab2 = 0.f, ab3 = 0.f;
        if (!last) {
            const int tok = (t == 0) ? x[row_own * TSTEPS]
                                     : label[row_own * TSTEPS + t - 1];
            const float* gi = Gimgb + (size_t)row_own * GD + col;
            const float* gt = Gtok  + (size_t)tok     * GD + col;
            ab0 = gi[0]    + gt[0];
            ab1 = gi[1024] + gt[1024];
            ab2 = gi[2048] + gt[2048];
            ab3 = gi[3072] + gt[3072];
        }
        float aval0 = 0.f, aval1 = 0.f, aval2 = 0.f, aval3 = 0.f;

        for (int st = 0; st < 4; ++st) {
            // ---- stage 16 h rows into LDS (rotated) ----
            {
                const float4* src = reinterpret_cast<const float4*>(
                    hbuf + (size_t)cur * (BB * HD))
                    + (size_t)(bgrp * 64 + st * 16) * 256;
                #pragma unroll
                for (int jj = 0; jj < 8; ++jj) {
                    int idx = tid + jj * 512;
                    int rl  = idx >> 8, c = idx & 255;
                    hlds4[rl * 256 + ((c + 4 * rl) & 255)] = src[idx];
                }
            }
            __syncthreads();

            // ---- logits for step t-1, rows st*16..st*16+15, vocab jgrp ----
            if (t > 0) {
                float s = 0.f;
                #pragma unroll
                for (int m = 0; m < 8; ++m) {
                    int c = m * 32 + kc;
                    float4 h4 = hlds4[dotid * 256 + ((c + 4 * dotid) & 255)];
                    float4 w4 = Wfc4[(size_t)jgrp * 256 + c];
                    s = fmaf(h4.x, w4.x, fmaf(h4.y, w4.y,
                        fmaf(h4.z, w4.z, fmaf(h4.w, w4.w, s))));
                }
                s += __shfl_xor(s, 1);  s += __shfl_xor(s, 2);
                s += __shfl_xor(s, 4);  s += __shfl_xor(s, 8);
                s += __shfl_xor(s, 16);
                if (kc == 0)
                    logits[((size_t)(bgrp * 64 + st * 16 + dotid) * TSTEPS
                            + (t - 1)) * VD + jgrp] = s + bfcv;
            }

            // ---- gate FMA: 2 passes of 8 rows ----
            if (!last) {
                #pragma unroll
                for (int p = 0; p < 2; ++p) {
                    float acc[4][8];
                    #pragma unroll
                    for (int g = 0; g < 4; ++g)
                        #pragma unroll
                        for (int r = 0; r < 8; ++r) acc[g][r] = 0.f;

                    #pragma unroll
                    for (int r = 0; r < 8; ++r) {
                        const int rl = p * 8 + r;
                        #pragma unroll
                        for (int i = 0; i < 4; ++i) {
                            float4 h4 = hlds4[rl * 256
                                              + ((i * 64 + L + 4 * rl) & 255)];
                            #pragma unroll
                            for (int g = 0; g < 4; ++g)
                                acc[g][r] = fmaf(wreg[g][i].x, h4.x,
                                             fmaf(wreg[g][i].y, h4.y,
                                              fmaf(wreg[g][i].z, h4.z,
                                               fmaf(wreg[g][i].w, h4.w,
                                                    acc[g][r]))));
                        }
                    }

                    // value-halving butterfly: 8 row-values -> owner lanes
                    const bool own = (pass_own == st * 2 + p);
                    #pragma unroll
                    for (int g = 0; g < 4; ++g) {
                        float s0 = bit0 ? acc[g][0] : acc[g][1];
                        float s1 = bit0 ? acc[g][2] : acc[g][3];
                        float s2 = bit0 ? acc[g][4] : acc[g][5];
                        float s3 = bit0 ? acc[g][6] : acc[g][7];
                        float p0 = (bit0 ? acc[g][1] : acc[g][0]) + __shfl_xor(s0, 1);
                        float p1 = (bit0 ? acc[g][3] : acc[g][2]) + __shfl_xor(s1, 1);
                        float p2 = (bit0 ? acc[g][5] : acc[g][4]) + __shfl_xor(s2, 1);
                        float p3 = (bit0 ? acc[g][7] : acc[g][6]) + __shfl_xor(s3, 1);
                        float q0 = (bit1 ? p1 : p0) + __shfl_xor(bit1 ? p0 : p1, 2);
                        float q1 = (bit1 ? p3 : p2) + __shfl_xor(bit1 ? p2 : p3, 2);
                        float u  = (bit2 ? q1 : q0) + __shfl_xor(bit2 ? q0 : q1, 4);
                        u += __shfl_xor(u, 8);
                        u += __shfl_xor(u, 16);
                        u += __shfl_xor(u, 32);
                        if (g == 0)      aval0 = own ? u : aval0;
                        else if (g == 1) aval1 = own ? u : aval1;
                        else if (g == 2) aval2 = own ? u : aval2;
                        else             aval3 = own ? u : aval3;
                    }
                }
            }
            __syncthreads();
        }

        if (!last) {
            // torch gate order: i, f, g, o
            float a0 = aval0 + ab0, a1 = aval1 + ab1;
            float a2 = aval2 + ab2, a3 = aval3 + ab3;
            float ig = 1.f / (1.f + expf(-a0));
            float fg = 1.f / (1.f + expf(-a1));
            float gg = tanhf(a2);
            float og = 1.f / (1.f + expf(-a3));
            c_reg = fmaf(fg, c_reg, ig * gg);
            float hnew = og * tanhf(c_reg);
            hbuf[(size_t)(cur ^ 1) * (BB * HD) + (size_t)row_own * HD + col] = hnew;
            grid.sync();
            cur ^= 1;
        }
    }
}

// ---------------- argmax (first-occurrence tie-break, preds as float) -------
__global__ void argmax_kernel(const float* __restrict__ logits,
                              float* __restrict__ preds) {
    int row = blockIdx.x * 4 + (threadIdx.x >> 6);   // 65536 rows
    int lane = threadIdx.x & 63;
    const float* r = logits + (size_t)row * VD;
    float v0 = r[lane * 2], v1 = r[lane * 2 + 1];
    float bv; int bi;
    if (v1 > v0) { bv = v1; bi = lane * 2 + 1; } else { bv = v0; bi = lane * 2; }
    #pragma unroll
    for (int d = 32; d >= 1; d >>= 1) {
        float ov = __shfl_down(bv, d);
        int   oi = __shfl_down(bi, d);
        if (ov > bv || (ov == bv && oi < bi)) { bv = ov; bi = oi; }
    }
    if (lane == 0) preds[row] = (float)bi;
}

// ---------------- launch ----------------------------------------------------
extern "C" void kernel_launch(void* const* d_in, const int* in_sizes, int n_in,
                              void* d_out, int out_size, void* d_ws, size_t ws_size,
                              hipStream_t stream) {
    const int*   input_img = (const int*)  d_in[0];
    const int*   x         = (const int*)  d_in[1];
    const int*   label     = (const int*)  d_in[2];
    const float* emb_img   = (const float*)d_in[3];
    const float* emb_char  = (const float*)d_in[4];
    const float* W_proj    = (const float*)d_in[5];
    const float* b_proj    = (const float*)d_in[6];
    const float* W_ih      = (const float*)d_in[7];
    const float* W_hh      = (const float*)d_in[8];
    const float* b_ih      = (const float*)d_in[9];
    const float* b_hh      = (const float*)d_in[10];
    const float* W_fc      = (const float*)d_in[11];
    const float* b_fc      = (const float*)d_in[12];

    float* ws     = (float*)d_ws;
    float* Wc     = ws;                          // 4096*160
    float* gb     = Wc + (size_t)GD * CD;        // 4096
    float* Gimgb  = gb + GD;                     // 128*4096
    float* Gtok   = Gimgb + (size_t)BB * GD;     // 128*4096
    float* hbuf   = Gtok + (size_t)VD * GD;      // 2*128*1024

    float* logits = (float*)d_out;               // 128*512*128
    float* preds  = logits + (size_t)BB * TSTEPS * VD;

    fold_wc_kernel  <<<(GD * CD + 255) / 256, 256, 0, stream>>>(W_ih, W_proj, b_proj, b_ih, b_hh, Wc, gb);
    fold_gimg_kernel<<<(BB * GD) / 256, 256, 0, stream>>>(emb_img, input_img, Wc, gb, Gimgb);
    fold_gtok_kernel<<<(VD * GD) / 256, 256, 0, stream>>>(emb_char, Wc, Gtok);
    hbuf_init_kernel<<<(2 * BB * HD) / 256, 256, 0, stream>>>(hbuf);

    void* args[] = { (void*)&W_hh, (void*)&Gimgb, (void*)&Gtok, (void*)&W_fc,
                     (void*)&b_fc, (void*)&x, (void*)&label, (void*)&hbuf, (void*)&logits };
    hipLaunchCooperativeKernel((void*)lstm_fused, dim3(256), dim3(512), args, 0, stream);

    argmax_kernel<<<(BB * TSTEPS) / 4, 256, 0, stream>>>(logits, preds);
}

// Round 5
// 21194.688 us; speedup vs baseline: 1.7386x; 1.4629x over previous
//
#include <hip/hip_runtime.h>
#include <hip/hip_cooperative_groups.h>
#include <cmath>

// Model dims
#define TSTEPS 512
#define BB     128      // batch
#define HD     1024     // hidden
#define GD     4096     // 4*H
#define VD     128      // vocab
#define ED     128      // char emb
#define IE     32       // img emb
#define CD     160      // IE+ED

// DPP cross-lane move on the VALU pipe (no LDS). ctrl must be an immediate.
#define DPPMOV(v, ctrl) \
    __int_as_float(__builtin_amdgcn_update_dpp(0, __float_as_int(v), (ctrl), 0xF, 0xF, true))
#define DPP_XOR7  0x141   // row_half_mirror: lane ^= 7
#define DPP_XOR1  0x0B1   // quad_perm [1,0,3,2]
#define DPP_XOR2  0x04E   // quad_perm [2,3,0,1]
#define DPP_XOR8  0x128   // row_ror:8 == lane ^= 8 within 16-lane row

// ---------------- Fold kernels (run once per launch, trivial cost) ----------

__global__ void fold_wc_kernel(const float* __restrict__ W_ih,
                               const float* __restrict__ W_proj,
                               const float* __restrict__ b_proj,
                               const float* __restrict__ b_ih,
                               const float* __restrict__ b_hh,
                               float* __restrict__ Wc,
                               float* __restrict__ gb) {
    int idx = blockIdx.x * 256 + threadIdx.x;
    if (idx < GD * CD) {
        int g = idx / CD, c = idx - g * CD;
        const float* wr = W_ih + g * ED;
        float s = 0.f;
        #pragma unroll 8
        for (int e = 0; e < ED; ++e) s = fmaf(wr[e], W_proj[e * CD + c], s);
        Wc[idx] = s;
    }
    if (idx < GD) {
        const float* wr = W_ih + idx * ED;
        float s = b_ih[idx] + b_hh[idx];
        #pragma unroll 8
        for (int e = 0; e < ED; ++e) s = fmaf(wr[e], b_proj[e], s);
        gb[idx] = s;
    }
}

__global__ void fold_gimg_kernel(const float* __restrict__ emb_img,
                                 const int* __restrict__ input_img,
                                 const float* __restrict__ Wc,
                                 const float* __restrict__ gb,
                                 float* __restrict__ Gimgb) {
    int idx = blockIdx.x * 256 + threadIdx.x;   // BB*GD
    int b = idx >> 12, g = idx & (GD - 1);
    const float* e = emb_img + (size_t)input_img[b] * IE;
    const float* w = Wc + g * CD;
    float s = gb[g];
    #pragma unroll
    for (int k = 0; k < IE; ++k) s = fmaf(e[k], w[k], s);
    Gimgb[idx] = s;
}

__global__ void fold_gtok_kernel(const float* __restrict__ emb_char,
                                 const float* __restrict__ Wc,
                                 float* __restrict__ Gtok) {
    int idx = blockIdx.x * 256 + threadIdx.x;   // VD*GD
    int v = idx >> 12, g = idx & (GD - 1);
    const float* e = emb_char + v * ED;
    const float* w = Wc + g * CD + IE;
    float s = 0.f;
    #pragma unroll 8
    for (int k = 0; k < ED; ++k) s = fmaf(e[k], w[k], s);
    Gtok[idx] = s;
}

// zero hbuf + barrier counters, build transposed token stream tokseq[t][b]
__global__ void init_kernel(const int* __restrict__ x,
                            const int* __restrict__ label,
                            int* __restrict__ tokseq,
                            float* __restrict__ hbuf,
                            unsigned* __restrict__ barcnt) {
    int idx = blockIdx.x * 256 + threadIdx.x;   // 1024 blocks * 256
    if (idx < 2 * BB * HD) hbuf[idx] = 0.f;
    if (idx < TSTEPS * BB) {
        int t = idx >> 7, b = idx & (BB - 1);
        tokseq[idx] = (t == 0) ? x[b * TSTEPS] : label[b * TSTEPS + t - 1];
    }
    if (idx < 128) barcnt[idx] = 0;
}

// ---------------- Persistent-register cooperative LSTM + fused logits ------
// 256 blocks x 1024 threads (1 block/CU, 16 waves/CU). Block: 32 rows x 16
// cols. Wave w -> col jgrp*16+w; lane L = 64-way interleaved k-split (f4
// chunks i*64+L) -> lane-dense conflict-free ds_read_b128. Weights 64 VGPR
// persistent. Lane L owns batch row bgrp*32+(L&31) (L^32 = replica).
// Butterfly: DPP value-halving (xor7/xor1/xor2) + sums (dpp xor8,
// ds_swizzle xor16, shfl xor32); capture pass (L>>3)&3 -> row L&31.
// Sync: 4 independent 64-block monotonic barriers (one per bgrp).
__global__ __launch_bounds__(1024) void lstm_fused(
    const float* __restrict__ W_hh,    // [4096][1024]
    const float* __restrict__ Gimgb,   // [128][4096]
    const float* __restrict__ Gtok,    // [128][4096]
    const float* __restrict__ Wfc,     // [128][1024]
    const float* __restrict__ bfc,     // [128]
    const int*   __restrict__ tokseq,  // [512][128]
    float*       __restrict__ hbuf,    // [2][128][1024]
    float*       __restrict__ logits,  // [128][512][128]
    unsigned*    __restrict__ barcnt)  // [4][32]
{
    __shared__ float4 hlds4[16 * 256];  // 64 KiB

    const int tid  = threadIdx.x;
    const int bid  = blockIdx.x;
    const int bgrp = bid >> 6;          // 0..3
    const int jgrp = bid & 63;          // 0..63
    const int w    = tid >> 6;          // 0..15
    const int L    = tid & 63;
    const int col  = jgrp * 16 + w;     // 0..1023
    const int lrow = L & 31;
    const int row_own = bgrp * 32 + lrow;
    const int pcap = (L >> 3) & 3;
    const bool b0 = (L & 1), b1 = ((L >> 1) & 1), b2 = ((L >> 2) & 1);

    const int kc = L & 31;
    const int v  = jgrp * 2 + (L >> 5);
    const float bfcv = bfc[v];

    const float4* __restrict__ Whh4 = reinterpret_cast<const float4*>(W_hh);
    const float4* __restrict__ Wfc4 = reinterpret_cast<const float4*>(Wfc);

    float4 wreg[4][4];
    #pragma unroll
    for (int g = 0; g < 4; ++g)
        #pragma unroll
        for (int i = 0; i < 4; ++i)
            wreg[g][i] = Whh4[(size_t)(g * HD + col) * 256 + i * 64 + L];

    unsigned* cnt = barcnt + bgrp * 32;

    float ab0, ab1, ab2, ab3;
    {
        const int tok = tokseq[row_own];
        const float* gi = Gimgb + (size_t)row_own * GD + col;
        const float* gt = Gtok  + (size_t)tok     * GD + col;
        ab0 = gi[0]    + gt[0];
        ab1 = gi[1024] + gt[1024];
        ab2 = gi[2048] + gt[2048];
        ab3 = gi[3072] + gt[3072];
    }

    float c_reg = 0.f;
    int cur = 0;

    #pragma unroll 1
    for (int t = 0; t <= TSTEPS; ++t) {
        const bool last = (t == TSTEPS);
        float aval0 = 0.f, aval1 = 0.f, aval2 = 0.f, aval3 = 0.f;

        const float4* hsrc = reinterpret_cast<const float4*>(
            hbuf + (size_t)cur * (BB * HD));

        #pragma unroll 1
        for (int st = 0; st < 2; ++st) {
            {
                const float4* src = hsrc + (size_t)(bgrp * 32 + st * 16) * 256;
                #pragma unroll
                for (int j = 0; j < 4; ++j)
                    hlds4[tid + j * 1024] = src[tid + j * 1024];
            }
            __syncthreads();

            if (t > 0) {
                float s = 0.f;
                #pragma unroll
                for (int m = 0; m < 8; ++m) {
                    float4 h4 = hlds4[w * 256 + m * 32 + kc];
                    float4 w4 = Wfc4[(size_t)v * 256 + m * 32 + kc];
                    s = fmaf(h4.x, w4.x, fmaf(h4.y, w4.y,
                        fmaf(h4.z, w4.z, fmaf(h4.w, w4.w, s))));
                }
                s += __shfl_xor(s, 1);  s += __shfl_xor(s, 2);
                s += __shfl_xor(s, 4);  s += __shfl_xor(s, 8);
                s += __shfl_xor(s, 16);
                if (kc == 0)
                    logits[((size_t)(bgrp * 32 + st * 16 + w) * TSTEPS
                            + (t - 1)) * VD + v] = s + bfcv;
            }

            if (!last) {
                #pragma unroll 1
                for (int p = 0; p < 2; ++p) {
                    float acc[4][8];
                    #pragma unroll
                    for (int g = 0; g < 4; ++g)
                        #pragma unroll
                        for (int r = 0; r < 8; ++r) acc[g][r] = 0.f;

                    #pragma unroll
                    for (int r = 0; r < 8; ++r) {
                        const int rl = p * 8 + r;
                        #pragma unroll
                        for (int i = 0; i < 4; ++i) {
                            float4 h4 = hlds4[rl * 256 + i * 64 + L];
                            #pragma unroll
                            for (int g = 0; g < 4; ++g)
                                acc[g][r] = fmaf(wreg[g][i].x, h4.x,
                                             fmaf(wreg[g][i].y, h4.y,
                                              fmaf(wreg[g][i].z, h4.z,
                                               fmaf(wreg[g][i].w, h4.w,
                                                    acc[g][r]))));
                        }
                    }

                    const bool own = (pcap == st * 2 + p);
                    #pragma unroll
                    for (int g = 0; g < 4; ++g) {
                        float m0 = b2 ? acc[g][4] : acc[g][0];
                        float s0 = b2 ? acc[g][0] : acc[g][4];
                        float m1 = b2 ? acc[g][5] : acc[g][1];
                        float s1 = b2 ? acc[g][1] : acc[g][5];
                        float m2 = b2 ? acc[g][6] : acc[g][2];
                        float s2 = b2 ? acc[g][2] : acc[g][6];
                        float m3 = b2 ? acc[g][7] : acc[g][3];
                        float s3 = b2 ? acc[g][3] : acc[g][7];
                        float n0 = m0 + DPPMOV(s0, DPP_XOR7);
                        float n1 = m1 + DPPMOV(s1, DPP_XOR7);
                        float n2 = m2 + DPPMOV(s2, DPP_XOR7);
                        float n3 = m3 + DPPMOV(s3, DPP_XOR7);
                        float p0k = b0 ? n1 : n0;
                        float p0s = b0 ? n0 : n1;
                        float p1k = b0 ? n3 : n2;
                        float p1s = b0 ? n2 : n3;
                        float q0 = p0k + DPPMOV(p0s, DPP_XOR1);
                        float q1 = p1k + DPPMOV(p1s, DPP_XOR1);
                        float rk = b1 ? q1 : q0;
                        float rs = b1 ? q0 : q1;
                        float u  = rk + DPPMOV(rs, DPP_XOR2);
                        u += DPPMOV(u, DPP_XOR8);
                        u += __int_as_float(__builtin_amdgcn_ds_swizzle(
                                 __float_as_int(u), 0x401F));   // xor16
                        u += __shfl_xor(u, 32);
                        if (g == 0)      aval0 = own ? u : aval0;
                        else if (g == 1) aval1 = own ? u : aval1;
                        else if (g == 2) aval2 = own ? u : aval2;
                        else             aval3 = own ? u : aval3;
                    }
                }
            }
            __syncthreads();
        }

        if (!last) {
            float a0 = aval0 + ab0, a1 = aval1 + ab1;
            float a2 = aval2 + ab2, a3 = aval3 + ab3;
            float ig = 1.f / (1.f + expf(-a0));
            float fg = 1.f / (1.f + expf(-a1));
            float gg = tanhf(a2);
            float og = 1.f / (1.f + expf(-a3));
            c_reg = fmaf(fg, c_reg, ig * gg);
            float hnew = og * tanhf(c_reg);
            if (L < 32)
                hbuf[(size_t)(cur ^ 1) * (BB * HD)
                     + (size_t)row_own * HD + col] = hnew;

            if (t + 1 < TSTEPS) {
                const int tok = tokseq[(t + 1) * BB + row_own];
                const float* gi = Gimgb + (size_t)row_own * GD + col;
                const float* gt = Gtok  + (size_t)tok     * GD + col;
                ab0 = gi[0]    + gt[0];
                ab1 = gi[1024] + gt[1024];
                ab2 = gi[2048] + gt[2048];
                ab3 = gi[3072] + gt[3072];
            }

            __syncthreads();
            if (tid == 0) {
                __hip_atomic_fetch_add(cnt, 1u, __ATOMIC_RELEASE,
                                       __HIP_MEMORY_SCOPE_AGENT);
                const unsigned target = 64u * (unsigned)(t + 1);
                while (__hip_atomic_load(cnt, __ATOMIC_ACQUIRE,
                                         __HIP_MEMORY_SCOPE_AGENT) < target)
                    __builtin_amdgcn_s_sleep(1);
            }
            __syncthreads();
            cur ^= 1;
        }
    }
}

// ---------------- argmax (first-occurrence tie-break, preds as float) -------
__global__ void argmax_kernel(const float* __restrict__ logits,
                              float* __restrict__ preds) {
    int row = blockIdx.x * 4 + (threadIdx.x >> 6);   // 65536 rows
    int lane = threadIdx.x & 63;
    const float* r = logits + (size_t)row * VD;
    float v0 = r[lane * 2], v1 = r[lane * 2 + 1];
    float bv; int bi;
    if (v1 > v0) { bv = v1; bi = lane * 2 + 1; } else { bv = v0; bi = lane * 2; }
    #pragma unroll
    for (int d = 32; d >= 1; d >>= 1) {
        float ov = __shfl_down(bv, d);
        int   oi = __shfl_down(bi, d);
        if (ov > bv || (ov == bv && oi < bi)) { bv = ov; bi = oi; }
    }
    if (lane == 0) preds[row] = (float)bi;
}

// ---------------- launch ----------------------------------------------------
extern "C" void kernel_launch(void* const* d_in, const int* in_sizes, int n_in,
                              void* d_out, int out_size, void* d_ws, size_t ws_size,
                              hipStream_t stream) {
    const int*   input_img = (const int*)  d_in[0];
    const int*   x         = (const int*)  d_in[1];
    const int*   label     = (const int*)  d_in[2];
    const float* emb_img   = (const float*)d_in[3];
    const float* emb_char  = (const float*)d_in[4];
    const float* W_proj    = (const float*)d_in[5];
    const float* b_proj    = (const float*)d_in[6];
    const float* W_ih      = (const float*)d_in[7];
    const float* W_hh      = (const float*)d_in[8];
    const float* b_ih      = (const float*)d_in[9];
    const float* b_hh      = (const float*)d_in[10];
    const float* W_fc      = (const float*)d_in[11];
    const float* b_fc      = (const float*)d_in[12];

    float* ws      = (float*)d_ws;
    float* Wc      = ws;                          // 4096*160
    float* gb      = Wc + (size_t)GD * CD;        // 4096
    float* Gimgb   = gb + GD;                     // 128*4096
    float* Gtok    = Gimgb + (size_t)BB * GD;     // 128*4096
    float* hbuf    = Gtok + (size_t)VD * GD;      // 2*128*1024
    int*   tokseq  = (int*)(hbuf + 2 * (size_t)BB * HD);   // 512*128 ints
    unsigned* barcnt = (unsigned*)(tokseq + TSTEPS * BB);  // 128 uints

    float* logits = (float*)d_out;               // 128*512*128
    float* preds  = logits + (size_t)BB * TSTEPS * VD;

    fold_wc_kernel  <<<(GD * CD + 255) / 256, 256, 0, stream>>>(W_ih, W_proj, b_proj, b_ih, b_hh, Wc, gb);
    fold_gimg_kernel<<<(BB * GD) / 256, 256, 0, stream>>>(emb_img, input_img, Wc, gb, Gimgb);
    fold_gtok_kernel<<<(VD * GD) / 256, 256, 0, stream>>>(emb_char, Wc, Gtok);
    init_kernel     <<<1024, 256, 0, stream>>>(x, label, tokseq, hbuf, barcnt);

    void* kargs[] = { (void*)&W_hh, (void*)&Gimgb, (void*)&Gtok, (void*)&W_fc,
                      (void*)&b_fc, (void*)&tokseq, (void*)&hbuf, (void*)&logits,
                      (void*)&barcnt };
    hipLaunchCooperativeKernel((void*)lstm_fused, dim3(256), dim3(1024), kargs, 0, stream);

    argmax_kernel<<<(BB * TSTEPS) / 4, 256, 0, stream>>>(logits, preds);
}

// Round 6
// 21050.414 us; speedup vs baseline: 1.7506x; 1.0069x over previous
//
#include <hip/hip_runtime.h>
#include <hip/hip_cooperative_groups.h>
#include <cmath>

// Model dims
#define TSTEPS 512
#define BB     128      // batch
#define HD     1024     // hidden
#define GD     4096     // 4*H
#define VD     128      // vocab
#define ED     128      // char emb
#define IE     32       // img emb
#define CD     160      // IE+ED

// DPP cross-lane move on the VALU pipe (no LDS). ctrl must be an immediate.
#define DPPMOV(v, ctrl) \
    __int_as_float(__builtin_amdgcn_update_dpp(0, __float_as_int(v), (ctrl), 0xF, 0xF, true))
#define DPP_XOR7  0x141   // row_half_mirror: lane ^= 7
#define DPP_XOR1  0x0B1   // quad_perm [1,0,3,2]
#define DPP_XOR2  0x04E   // quad_perm [2,3,0,1]
#define DPP_XOR8  0x128   // row_ror:8 == lane ^= 8 within 16-lane row

// ---------------- Fold kernels (run once per launch, trivial cost) ----------

__global__ void fold_wc_kernel(const float* __restrict__ W_ih,
                               const float* __restrict__ W_proj,
                               const float* __restrict__ b_proj,
                               const float* __restrict__ b_ih,
                               const float* __restrict__ b_hh,
                               float* __restrict__ Wc,
                               float* __restrict__ gb) {
    int idx = blockIdx.x * 256 + threadIdx.x;
    if (idx < GD * CD) {
        int g = idx / CD, c = idx - g * CD;
        const float* wr = W_ih + g * ED;
        float s = 0.f;
        #pragma unroll 8
        for (int e = 0; e < ED; ++e) s = fmaf(wr[e], W_proj[e * CD + c], s);
        Wc[idx] = s;
    }
    if (idx < GD) {
        const float* wr = W_ih + idx * ED;
        float s = b_ih[idx] + b_hh[idx];
        #pragma unroll 8
        for (int e = 0; e < ED; ++e) s = fmaf(wr[e], b_proj[e], s);
        gb[idx] = s;
    }
}

__global__ void fold_gimg_kernel(const float* __restrict__ emb_img,
                                 const int* __restrict__ input_img,
                                 const float* __restrict__ Wc,
                                 const float* __restrict__ gb,
                                 float* __restrict__ Gimgb) {
    int idx = blockIdx.x * 256 + threadIdx.x;   // BB*GD
    int b = idx >> 12, g = idx & (GD - 1);
    const float* e = emb_img + (size_t)input_img[b] * IE;
    const float* w = Wc + g * CD;
    float s = gb[g];
    #pragma unroll
    for (int k = 0; k < IE; ++k) s = fmaf(e[k], w[k], s);
    Gimgb[idx] = s;
}

__global__ void fold_gtok_kernel(const float* __restrict__ emb_char,
                                 const float* __restrict__ Wc,
                                 float* __restrict__ Gtok) {
    int idx = blockIdx.x * 256 + threadIdx.x;   // VD*GD
    int v = idx >> 12, g = idx & (GD - 1);
    const float* e = emb_char + v * ED;
    const float* w = Wc + g * CD + IE;
    float s = 0.f;
    #pragma unroll 8
    for (int k = 0; k < ED; ++k) s = fmaf(e[k], w[k], s);
    Gtok[idx] = s;
}

// zero hbuf + barrier counters, build transposed token stream tokseq[t][b]
__global__ void init_kernel(const int* __restrict__ x,
                            const int* __restrict__ label,
                            int* __restrict__ tokseq,
                            float* __restrict__ hbuf,
                            unsigned* __restrict__ barcnt) {
    int idx = blockIdx.x * 256 + threadIdx.x;   // 1024 blocks * 256
    if (idx < 2 * BB * HD) hbuf[idx] = 0.f;
    if (idx < TSTEPS * BB) {
        int t = idx >> 7, b = idx & (BB - 1);
        tokseq[idx] = (t == 0) ? x[b * TSTEPS] : label[b * TSTEPS + t - 1];
    }
    if (idx < 128) barcnt[idx] = 0;
}

// ---------------- Persistent-register cooperative LSTM + fused logits ------
// 256 blocks x 1024 threads (1 block/CU, 16 waves/CU). Block: 32 rows x 16
// cols. Wave w -> col jgrp*16+w; lane L = 64-way interleaved k-split (f4
// chunks i*64+L) -> lane-dense conflict-free ds_read_b128. Weights 64 VGPR
// persistent. Lane L owns batch row bgrp*32+(L&31) (L^32 = replica).
// Butterfly: DPP value-halving (xor7/xor1/xor2) + sums (dpp xor8,
// ds_swizzle xor16, shfl xor32); capture pass (L>>3)&3 -> row L&31.
// Sync: 4 independent 64-block monotonic barriers (one per bgrp).
// __launch_bounds__(1024, 4): 4 waves/EU == our exact occupancy -> VGPR
// budget 128, so the 64-VGPR weight set stays RESIDENT (R5's (1024) default
// targeted 8 waves/EU -> 64 VGPR cap -> spill, FETCH 12.2 GB).
__global__ __launch_bounds__(1024, 4) void lstm_fused(
    const float* __restrict__ W_hh,    // [4096][1024]
    const float* __restrict__ Gimgb,   // [128][4096]
    const float* __restrict__ Gtok,    // [128][4096]
    const float* __restrict__ Wfc,     // [128][1024]
    const float* __restrict__ bfc,     // [128]
    const int*   __restrict__ tokseq,  // [512][128]
    float*       __restrict__ hbuf,    // [2][128][1024]
    float*       __restrict__ logits,  // [128][512][128]
    unsigned*    __restrict__ barcnt)  // [4][32]
{
    __shared__ float4 hlds4[16 * 256];  // 64 KiB

    const int tid  = threadIdx.x;
    const int bid  = blockIdx.x;
    const int bgrp = bid >> 6;          // 0..3
    const int jgrp = bid & 63;          // 0..63
    const int w    = tid >> 6;          // 0..15
    const int L    = tid & 63;
    const int col  = jgrp * 16 + w;     // 0..1023
    const int lrow = L & 31;
    const int row_own = bgrp * 32 + lrow;
    const int pcap = (L >> 3) & 3;
    const bool b0 = (L & 1), b1 = ((L >> 1) & 1), b2 = ((L >> 2) & 1);

    const int kc = L & 31;
    const int v  = jgrp * 2 + (L >> 5);
    const float bfcv = bfc[v];

    const float4* __restrict__ Whh4 = reinterpret_cast<const float4*>(W_hh);
    const float4* __restrict__ Wfc4 = reinterpret_cast<const float4*>(Wfc);

    float4 wreg[4][4];
    #pragma unroll
    for (int g = 0; g < 4; ++g)
        #pragma unroll
        for (int i = 0; i < 4; ++i)
            wreg[g][i] = Whh4[(size_t)(g * HD + col) * 256 + i * 64 + L];

    unsigned* cnt = barcnt + bgrp * 32;

    float ab0, ab1, ab2, ab3;
    {
        const int tok = tokseq[row_own];
        const float* gi = Gimgb + (size_t)row_own * GD + col;
        const float* gt = Gtok  + (size_t)tok     * GD + col;
        ab0 = gi[0]    + gt[0];
        ab1 = gi[1024] + gt[1024];
        ab2 = gi[2048] + gt[2048];
        ab3 = gi[3072] + gt[3072];
    }

    float c_reg = 0.f;
    int cur = 0;

    #pragma unroll 1
    for (int t = 0; t <= TSTEPS; ++t) {
        const bool last = (t == TSTEPS);
        float aval0 = 0.f, aval1 = 0.f, aval2 = 0.f, aval3 = 0.f;

        const float4* hsrc = reinterpret_cast<const float4*>(
            hbuf + (size_t)cur * (BB * HD));

        #pragma unroll 1
        for (int st = 0; st < 2; ++st) {
            {
                const float4* src = hsrc + (size_t)(bgrp * 32 + st * 16) * 256;
                #pragma unroll
                for (int j = 0; j < 4; ++j)
                    hlds4[tid + j * 1024] = src[tid + j * 1024];
            }
            __syncthreads();

            if (t > 0) {
                float s = 0.f;
                #pragma unroll
                for (int m = 0; m < 8; ++m) {
                    float4 h4 = hlds4[w * 256 + m * 32 + kc];
                    float4 w4 = Wfc4[(size_t)v * 256 + m * 32 + kc];
                    s = fmaf(h4.x, w4.x, fmaf(h4.y, w4.y,
                        fmaf(h4.z, w4.z, fmaf(h4.w, w4.w, s))));
                }
                s += __shfl_xor(s, 1);  s += __shfl_xor(s, 2);
                s += __shfl_xor(s, 4);  s += __shfl_xor(s, 8);
                s += __shfl_xor(s, 16);
                if (kc == 0)
                    logits[((size_t)(bgrp * 32 + st * 16 + w) * TSTEPS
                            + (t - 1)) * VD + v] = s + bfcv;
            }

            if (!last) {
                #pragma unroll 1
                for (int p = 0; p < 2; ++p) {
                    float acc[4][8];
                    #pragma unroll
                    for (int g = 0; g < 4; ++g)
                        #pragma unroll
                        for (int r = 0; r < 8; ++r) acc[g][r] = 0.f;

                    #pragma unroll
                    for (int r = 0; r < 8; ++r) {
                        const int rl = p * 8 + r;
                        #pragma unroll
                        for (int i = 0; i < 4; ++i) {
                            float4 h4 = hlds4[rl * 256 + i * 64 + L];
                            #pragma unroll
                            for (int g = 0; g < 4; ++g)
                                acc[g][r] = fmaf(wreg[g][i].x, h4.x,
                                             fmaf(wreg[g][i].y, h4.y,
                                              fmaf(wreg[g][i].z, h4.z,
                                               fmaf(wreg[g][i].w, h4.w,
                                                    acc[g][r]))));
                        }
                    }

                    const bool own = (pcap == st * 2 + p);
                    #pragma unroll
                    for (int g = 0; g < 4; ++g) {
                        float m0 = b2 ? acc[g][4] : acc[g][0];
                        float s0 = b2 ? acc[g][0] : acc[g][4];
                        float m1 = b2 ? acc[g][5] : acc[g][1];
                        float s1 = b2 ? acc[g][1] : acc[g][5];
                        float m2 = b2 ? acc[g][6] : acc[g][2];
                        float s2 = b2 ? acc[g][2] : acc[g][6];
                        float m3 = b2 ? acc[g][7] : acc[g][3];
                        float s3 = b2 ? acc[g][3] : acc[g][7];
                        float n0 = m0 + DPPMOV(s0, DPP_XOR7);
                        float n1 = m1 + DPPMOV(s1, DPP_XOR7);
                        float n2 = m2 + DPPMOV(s2, DPP_XOR7);
                        float n3 = m3 + DPPMOV(s3, DPP_XOR7);
                        float p0k = b0 ? n1 : n0;
                        float p0s = b0 ? n0 : n1;
                        float p1k = b0 ? n3 : n2;
                        float p1s = b0 ? n2 : n3;
                        float q0 = p0k + DPPMOV(p0s, DPP_XOR1);
                        float q1 = p1k + DPPMOV(p1s, DPP_XOR1);
                        float rk = b1 ? q1 : q0;
                        float rs = b1 ? q0 : q1;
                        float u  = rk + DPPMOV(rs, DPP_XOR2);
                        u += DPPMOV(u, DPP_XOR8);
                        u += __int_as_float(__builtin_amdgcn_ds_swizzle(
                                 __float_as_int(u), 0x401F));   // xor16
                        u += __shfl_xor(u, 32);
                        if (g == 0)      aval0 = own ? u : aval0;
                        else if (g == 1) aval1 = own ? u : aval1;
                        else if (g == 2) aval2 = own ? u : aval2;
                        else             aval3 = own ? u : aval3;
                    }
                }
            }
            __syncthreads();
        }

        if (!last) {
            float a0 = aval0 + ab0, a1 = aval1 + ab1;
            float a2 = aval2 + ab2, a3 = aval3 + ab3;
            float ig = 1.f / (1.f + expf(-a0));
            float fg = 1.f / (1.f + expf(-a1));
            float gg = tanhf(a2);
            float og = 1.f / (1.f + expf(-a3));
            c_reg = fmaf(fg, c_reg, ig * gg);
            float hnew = og * tanhf(c_reg);
            if (L < 32)
                hbuf[(size_t)(cur ^ 1) * (BB * HD)
                     + (size_t)row_own * HD + col] = hnew;

            if (t + 1 < TSTEPS) {
                const int tok = tokseq[(t + 1) * BB + row_own];
                const float* gi = Gimgb + (size_t)row_own * GD + col;
                const float* gt = Gtok  + (size_t)tok     * GD + col;
                ab0 = gi[0]    + gt[0];
                ab1 = gi[1024] + gt[1024];
                ab2 = gi[2048] + gt[2048];
                ab3 = gi[3072] + gt[3072];
            }

            __syncthreads();
            if (tid == 0) {
                __hip_atomic_fetch_add(cnt, 1u, __ATOMIC_RELEASE,
                                       __HIP_MEMORY_SCOPE_AGENT);
                const unsigned target = 64u * (unsigned)(t + 1);
                while (__hip_atomic_load(cnt, __ATOMIC_ACQUIRE,
                                         __HIP_MEMORY_SCOPE_AGENT) < target)
                    __builtin_amdgcn_s_sleep(1);
            }
            __syncthreads();
            cur ^= 1;
        }
    }
}

// ---------------- argmax (first-occurrence tie-break, preds as float) -------
__global__ void argmax_kernel(const float* __restrict__ logits,
                              float* __restrict__ preds) {
    int row = blockIdx.x * 4 + (threadIdx.x >> 6);   // 65536 rows
    int lane = threadIdx.x & 63;
    const float* r = logits + (size_t)row * VD;
    float v0 = r[lane * 2], v1 = r[lane * 2 + 1];
    float bv; int bi;
    if (v1 > v0) { bv = v1; bi = lane * 2 + 1; } else { bv = v0; bi = lane * 2; }
    #pragma unroll
    for (int d = 32; d >= 1; d >>= 1) {
        float ov = __shfl_down(bv, d);
        int   oi = __shfl_down(bi, d);
        if (ov > bv || (ov == bv && oi < bi)) { bv = ov; bi = oi; }
    }
    if (lane == 0) preds[row] = (float)bi;
}

// ---------------- launch ----------------------------------------------------
extern "C" void kernel_launch(void* const* d_in, const int* in_sizes, int n_in,
                              void* d_out, int out_size, void* d_ws, size_t ws_size,
                              hipStream_t stream) {
    const int*   input_img = (const int*)  d_in[0];
    const int*   x         = (const int*)  d_in[1];
    const int*   label     = (const int*)  d_in[2];
    const float* emb_img   = (const float*)d_in[3];
    const float* emb_char  = (const float*)d_in[4];
    const float* W_proj    = (const float*)d_in[5];
    const float* b_proj    = (const float*)d_in[6];
    const float* W_ih      = (const float*)d_in[7];
    const float* W_hh      = (const float*)d_in[8];
    const float* b_ih      = (const float*)d_in[9];
    const float* b_hh      = (const float*)d_in[10];
    const float* W_fc      = (const float*)d_in[11];
    const float* b_fc      = (const float*)d_in[12];

    float* ws      = (float*)d_ws;
    float* Wc      = ws;                          // 4096*160
    float* gb      = Wc + (size_t)GD * CD;        // 4096
    float* Gimgb   = gb + GD;                     // 128*4096
    float* Gtok    = Gimgb + (size_t)BB * GD;     // 128*4096
    float* hbuf    = Gtok + (size_t)VD * GD;      // 2*128*1024
    int*   tokseq  = (int*)(hbuf + 2 * (size_t)BB * HD);   // 512*128 ints
    unsigned* barcnt = (unsigned*)(tokseq + TSTEPS * BB);  // 128 uints

    float* logits = (float*)d_out;               // 128*512*128
    float* preds  = logits + (size_t)BB * TSTEPS * VD;

    fold_wc_kernel  <<<(GD * CD + 255) / 256, 256, 0, stream>>>(W_ih, W_proj, b_proj, b_ih, b_hh, Wc, gb);
    fold_gimg_kernel<<<(BB * GD) / 256, 256, 0, stream>>>(emb_img, input_img, Wc, gb, Gimgb);
    fold_gtok_kernel<<<(VD * GD) / 256, 256, 0, stream>>>(emb_char, Wc, Gtok);
    init_kernel     <<<1024, 256, 0, stream>>>(x, label, tokseq, hbuf, barcnt);

    void* kargs[] = { (void*)&W_hh, (void*)&Gimgb, (void*)&Gtok, (void*)&W_fc,
                      (void*)&b_fc, (void*)&tokseq, (void*)&hbuf, (void*)&logits,
                      (void*)&barcnt };
    hipLaunchCooperativeKernel((void*)lstm_fused, dim3(256), dim3(1024), kargs, 0, stream);

    argmax_kernel<<<(BB * TSTEPS) / 4, 256, 0, stream>>>(logits, preds);
}

// Round 7
// 20709.584 us; speedup vs baseline: 1.7794x; 1.0165x over previous
//
#include <hip/hip_runtime.h>
#include <hip/hip_cooperative_groups.h>
#include <cmath>

// Model dims
#define TSTEPS 512
#define BB     128      // batch
#define HD     1024     // hidden
#define GD     4096     // 4*H
#define VD     128      // vocab
#define ED     128      // char emb
#define IE     32       // img emb
#define CD     160      // IE+ED

// DPP cross-lane move on the VALU pipe (no LDS). ctrl must be an immediate.
#define DPPMOV(v, ctrl) \
    __int_as_float(__builtin_amdgcn_update_dpp(0, __float_as_int(v), (ctrl), 0xF, 0xF, true))
#define DPP_XOR7  0x141   // row_half_mirror: lane ^= 7
#define DPP_XOR1  0x0B1   // quad_perm [1,0,3,2]
#define DPP_XOR2  0x04E   // quad_perm [2,3,0,1]
#define DPP_XOR8  0x128   // row_ror:8 == lane ^= 8 within 16-lane row

// ---------------- Fold kernels (run once per launch, trivial cost) ----------

__global__ void fold_wc_kernel(const float* __restrict__ W_ih,
                               const float* __restrict__ W_proj,
                               const float* __restrict__ b_proj,
                               const float* __restrict__ b_ih,
                               const float* __restrict__ b_hh,
                               float* __restrict__ Wc,
                               float* __restrict__ gb) {
    int idx = blockIdx.x * 256 + threadIdx.x;
    if (idx < GD * CD) {
        int g = idx / CD, c = idx - g * CD;
        const float* wr = W_ih + g * ED;
        float s = 0.f;
        #pragma unroll 8
        for (int e = 0; e < ED; ++e) s = fmaf(wr[e], W_proj[e * CD + c], s);
        Wc[idx] = s;
    }
    if (idx < GD) {
        const float* wr = W_ih + idx * ED;
        float s = b_ih[idx] + b_hh[idx];
        #pragma unroll 8
        for (int e = 0; e < ED; ++e) s = fmaf(wr[e], b_proj[e], s);
        gb[idx] = s;
    }
}

__global__ void fold_gimg_kernel(const float* __restrict__ emb_img,
                                 const int* __restrict__ input_img,
                                 const float* __restrict__ Wc,
                                 const float* __restrict__ gb,
                                 float* __restrict__ Gimgb) {
    int idx = blockIdx.x * 256 + threadIdx.x;   // BB*GD
    int b = idx >> 12, g = idx & (GD - 1);
    const float* e = emb_img + (size_t)input_img[b] * IE;
    const float* w = Wc + g * CD;
    float s = gb[g];
    #pragma unroll
    for (int k = 0; k < IE; ++k) s = fmaf(e[k], w[k], s);
    Gimgb[idx] = s;
}

__global__ void fold_gtok_kernel(const float* __restrict__ emb_char,
                                 const float* __restrict__ Wc,
                                 float* __restrict__ Gtok) {
    int idx = blockIdx.x * 256 + threadIdx.x;   // VD*GD
    int v = idx >> 12, g = idx & (GD - 1);
    const float* e = emb_char + v * ED;
    const float* w = Wc + g * CD + IE;
    float s = 0.f;
    #pragma unroll 8
    for (int k = 0; k < ED; ++k) s = fmaf(e[k], w[k], s);
    Gtok[idx] = s;
}

// zero hbuf + barrier counters, build transposed token stream tokseq[t][b]
__global__ void init_kernel(const int* __restrict__ x,
                            const int* __restrict__ label,
                            int* __restrict__ tokseq,
                            float* __restrict__ hbuf,
                            unsigned* __restrict__ barcnt) {
    int idx = blockIdx.x * 256 + threadIdx.x;   // 1024 blocks * 256
    if (idx < 2 * BB * HD) hbuf[idx] = 0.f;
    if (idx < TSTEPS * BB) {
        int t = idx >> 7, b = idx & (BB - 1);
        tokseq[idx] = (t == 0) ? x[b * TSTEPS] : label[b * TSTEPS + t - 1];
    }
    if (idx < 128) barcnt[idx] = 0;
}

// ---------------- Persistent-register cooperative LSTM + fused logits ------
// 256 blocks x 1024 threads (1 block/CU, 16 waves/CU). Block: 32 rows x 16
// cols. Wave w -> col jgrp*16+w; lane L = 64-way interleaved k-split (f4
// chunks i*64+L) -> lane-dense conflict-free ds_read_b128. Weights 64 VGPR
// persistent — loads PINNED via asm "+v" barrier so the allocator cannot
// rematerialize them in-loop (R6: it chose 64 VGPRs and re-streamed 24
// MB/step of weights; launch_bounds only bounds, doesn't target).
// Lane L owns batch row bgrp*32+(L&31) (L^32 = replica).
// Butterfly: DPP value-halving (xor7/xor1/xor2) + sums (dpp xor8,
// ds_swizzle xor16, shfl xor32); capture pass (L>>3)&3 -> row L&31.
// Sync: 4 independent 64-block monotonic barriers (one per bgrp).
__global__ __launch_bounds__(1024, 4) void lstm_fused(
    const float* __restrict__ W_hh,    // [4096][1024]
    const float* __restrict__ Gimgb,   // [128][4096]
    const float* __restrict__ Gtok,    // [128][4096]
    const float* __restrict__ Wfc,     // [128][1024]
    const float* __restrict__ bfc,     // [128]
    const int*   __restrict__ tokseq,  // [512][128]
    float*       __restrict__ hbuf,    // [2][128][1024]
    float*       __restrict__ logits,  // [128][512][128]
    unsigned*    __restrict__ barcnt)  // [4][32]
{
    __shared__ float4 hlds4[16 * 256];  // 64 KiB

    const int tid  = threadIdx.x;
    const int bid  = blockIdx.x;
    const int bgrp = bid >> 6;          // 0..3
    const int jgrp = bid & 63;          // 0..63
    const int w    = tid >> 6;          // 0..15
    const int L    = tid & 63;
    const int col  = jgrp * 16 + w;     // 0..1023
    const int lrow = L & 31;
    const int row_own = bgrp * 32 + lrow;
    const int pcap = (L >> 3) & 3;
    const bool b0 = (L & 1), b1 = ((L >> 1) & 1), b2 = ((L >> 2) & 1);

    const int kc = L & 31;
    const int v  = jgrp * 2 + (L >> 5);
    const float bfcv = bfc[v];

    const float4* __restrict__ Whh4 = reinterpret_cast<const float4*>(W_hh);
    const float4* __restrict__ Wfc4 = reinterpret_cast<const float4*>(Wfc);

    float4 wreg[4][4];
    #pragma unroll
    for (int g = 0; g < 4; ++g)
        #pragma unroll
        for (int i = 0; i < 4; ++i)
            wreg[g][i] = Whh4[(size_t)(g * HD + col) * 256 + i * 64 + L];

    // PIN the weight set: asm "+v" makes each value opaque (cannot be
    // rematerialized from W_hh) -> must stay VGPR-resident for the loop.
    #pragma unroll
    for (int g = 0; g < 4; ++g)
        #pragma unroll
        for (int i = 0; i < 4; ++i)
            asm volatile("" : "+v"(wreg[g][i].x), "+v"(wreg[g][i].y),
                              "+v"(wreg[g][i].z), "+v"(wreg[g][i].w));

    unsigned* cnt = barcnt + bgrp * 32;

    float ab0, ab1, ab2, ab3;
    {
        const int tok = tokseq[row_own];
        const float* gi = Gimgb + (size_t)row_own * GD + col;
        const float* gt = Gtok  + (size_t)tok     * GD + col;
        ab0 = gi[0]    + gt[0];
        ab1 = gi[1024] + gt[1024];
        ab2 = gi[2048] + gt[2048];
        ab3 = gi[3072] + gt[3072];
    }

    float c_reg = 0.f;
    int cur = 0;

    #pragma unroll 1
    for (int t = 0; t <= TSTEPS; ++t) {
        const bool last = (t == TSTEPS);
        float aval0 = 0.f, aval1 = 0.f, aval2 = 0.f, aval3 = 0.f;

        const float4* hsrc = reinterpret_cast<const float4*>(
            hbuf + (size_t)cur * (BB * HD));

        #pragma unroll 1
        for (int st = 0; st < 2; ++st) {
            {
                const float4* src = hsrc + (size_t)(bgrp * 32 + st * 16) * 256;
                #pragma unroll
                for (int j = 0; j < 4; ++j)
                    hlds4[tid + j * 1024] = src[tid + j * 1024];
            }
            __syncthreads();

            if (t > 0) {
                float s = 0.f;
                #pragma unroll
                for (int m = 0; m < 8; ++m) {
                    float4 h4 = hlds4[w * 256 + m * 32 + kc];
                    float4 w4 = Wfc4[(size_t)v * 256 + m * 32 + kc];
                    s = fmaf(h4.x, w4.x, fmaf(h4.y, w4.y,
                        fmaf(h4.z, w4.z, fmaf(h4.w, w4.w, s))));
                }
                s += __shfl_xor(s, 1);  s += __shfl_xor(s, 2);
                s += __shfl_xor(s, 4);  s += __shfl_xor(s, 8);
                s += __shfl_xor(s, 16);
                if (kc == 0)
                    logits[((size_t)(bgrp * 32 + st * 16 + w) * TSTEPS
                            + (t - 1)) * VD + v] = s + bfcv;
            }

            if (!last) {
                #pragma unroll 1
                for (int p = 0; p < 2; ++p) {
                    float acc[4][8];
                    #pragma unroll
                    for (int g = 0; g < 4; ++g)
                        #pragma unroll
                        for (int r = 0; r < 8; ++r) acc[g][r] = 0.f;

                    #pragma unroll
                    for (int r = 0; r < 8; ++r) {
                        const int rl = p * 8 + r;
                        #pragma unroll
                        for (int i = 0; i < 4; ++i) {
                            float4 h4 = hlds4[rl * 256 + i * 64 + L];
                            #pragma unroll
                            for (int g = 0; g < 4; ++g)
                                acc[g][r] = fmaf(wreg[g][i].x, h4.x,
                                             fmaf(wreg[g][i].y, h4.y,
                                              fmaf(wreg[g][i].z, h4.z,
                                               fmaf(wreg[g][i].w, h4.w,
                                                    acc[g][r]))));
                        }
                    }

                    const bool own = (pcap == st * 2 + p);
                    #pragma unroll
                    for (int g = 0; g < 4; ++g) {
                        float m0 = b2 ? acc[g][4] : acc[g][0];
                        float s0 = b2 ? acc[g][0] : acc[g][4];
                        float m1 = b2 ? acc[g][5] : acc[g][1];
                        float s1 = b2 ? acc[g][1] : acc[g][5];
                        float m2 = b2 ? acc[g][6] : acc[g][2];
                        float s2 = b2 ? acc[g][2] : acc[g][6];
                        float m3 = b2 ? acc[g][7] : acc[g][3];
                        float s3 = b2 ? acc[g][3] : acc[g][7];
                        float n0 = m0 + DPPMOV(s0, DPP_XOR7);
                        float n1 = m1 + DPPMOV(s1, DPP_XOR7);
                        float n2 = m2 + DPPMOV(s2, DPP_XOR7);
                        float n3 = m3 + DPPMOV(s3, DPP_XOR7);
                        float p0k = b0 ? n1 : n0;
                        float p0s = b0 ? n0 : n1;
                        float p1k = b0 ? n3 : n2;
                        float p1s = b0 ? n2 : n3;
                        float q0 = p0k + DPPMOV(p0s, DPP_XOR1);
                        float q1 = p1k + DPPMOV(p1s, DPP_XOR1);
                        float rk = b1 ? q1 : q0;
                        float rs = b1 ? q0 : q1;
                        float u  = rk + DPPMOV(rs, DPP_XOR2);
                        u += DPPMOV(u, DPP_XOR8);
                        u += __int_as_float(__builtin_amdgcn_ds_swizzle(
                                 __float_as_int(u), 0x401F));   // xor16
                        u += __shfl_xor(u, 32);
                        if (g == 0)      aval0 = own ? u : aval0;
                        else if (g == 1) aval1 = own ? u : aval1;
                        else if (g == 2) aval2 = own ? u : aval2;
                        else             aval3 = own ? u : aval3;
                    }
                }
            }
            __syncthreads();
        }

        if (!last) {
            float a0 = aval0 + ab0, a1 = aval1 + ab1;
            float a2 = aval2 + ab2, a3 = aval3 + ab3;
            float ig = 1.f / (1.f + expf(-a0));
            float fg = 1.f / (1.f + expf(-a1));
            float gg = tanhf(a2);
            float og = 1.f / (1.f + expf(-a3));
            c_reg = fmaf(fg, c_reg, ig * gg);
            float hnew = og * tanhf(c_reg);
            if (L < 32)
                hbuf[(size_t)(cur ^ 1) * (BB * HD)
                     + (size_t)row_own * HD + col] = hnew;

            if (t + 1 < TSTEPS) {
                const int tok = tokseq[(t + 1) * BB + row_own];
                const float* gi = Gimgb + (size_t)row_own * GD + col;
                const float* gt = Gtok  + (size_t)tok     * GD + col;
                ab0 = gi[0]    + gt[0];
                ab1 = gi[1024] + gt[1024];
                ab2 = gi[2048] + gt[2048];
                ab3 = gi[3072] + gt[3072];
            }

            __syncthreads();
            if (tid == 0) {
                __hip_atomic_fetch_add(cnt, 1u, __ATOMIC_RELEASE,
                                       __HIP_MEMORY_SCOPE_AGENT);
                const unsigned target = 64u * (unsigned)(t + 1);
                while (__hip_atomic_load(cnt, __ATOMIC_ACQUIRE,
                                         __HIP_MEMORY_SCOPE_AGENT) < target)
                    __builtin_amdgcn_s_sleep(1);
            }
            __syncthreads();
            cur ^= 1;
        }
    }
}

// ---------------- argmax (first-occurrence tie-break, preds as float) -------
__global__ void argmax_kernel(const float* __restrict__ logits,
                              float* __restrict__ preds) {
    int row = blockIdx.x * 4 + (threadIdx.x >> 6);   // 65536 rows
    int lane = threadIdx.x & 63;
    const float* r = logits + (size_t)row * VD;
    float v0 = r[lane * 2], v1 = r[lane * 2 + 1];
    float bv; int bi;
    if (v1 > v0) { bv = v1; bi = lane * 2 + 1; } else { bv = v0; bi = lane * 2; }
    #pragma unroll
    for (int d = 32; d >= 1; d >>= 1) {
        float ov = __shfl_down(bv, d);
        int   oi = __shfl_down(bi, d);
        if (ov > bv || (ov == bv && oi < bi)) { bv = ov; bi = oi; }
    }
    if (lane == 0) preds[row] = (float)bi;
}

// ---------------- launch ----------------------------------------------------
extern "C" void kernel_launch(void* const* d_in, const int* in_sizes, int n_in,
                              void* d_out, int out_size, void* d_ws, size_t ws_size,
                              hipStream_t stream) {
    const int*   input_img = (const int*)  d_in[0];
    const int*   x         = (const int*)  d_in[1];
    const int*   label     = (const int*)  d_in[2];
    const float* emb_img   = (const float*)d_in[3];
    const float* emb_char  = (const float*)d_in[4];
    const float* W_proj    = (const float*)d_in[5];
    const float* b_proj    = (const float*)d_in[6];
    const float* W_ih      = (const float*)d_in[7];
    const float* W_hh      = (const float*)d_in[8];
    const float* b_ih      = (const float*)d_in[9];
    const float* b_hh      = (const float*)d_in[10];
    const float* W_fc      = (const float*)d_in[11];
    const float* b_fc      = (const float*)d_in[12];

    float* ws      = (float*)d_ws;
    float* Wc      = ws;                          // 4096*160
    float* gb      = Wc + (size_t)GD * CD;        // 4096
    float* Gimgb   = gb + GD;                     // 128*4096
    float* Gtok    = Gimgb + (size_t)BB * GD;     // 128*4096
    float* hbuf    = Gtok + (size_t)VD * GD;      // 2*128*1024
    int*   tokseq  = (int*)(hbuf + 2 * (size_t)BB * HD);   // 512*128 ints
    unsigned* barcnt = (unsigned*)(tokseq + TSTEPS * BB);  // 128 uints

    float* logits = (float*)d_out;               // 128*512*128
    float* preds  = logits + (size_t)BB * TSTEPS * VD;

    fold_wc_kernel  <<<(GD * CD + 255) / 256, 256, 0, stream>>>(W_ih, W_proj, b_proj, b_ih, b_hh, Wc, gb);
    fold_gimg_kernel<<<(BB * GD) / 256, 256, 0, stream>>>(emb_img, input_img, Wc, gb, Gimgb);
    fold_gtok_kernel<<<(VD * GD) / 256, 256, 0, stream>>>(emb_char, Wc, Gtok);
    init_kernel     <<<1024, 256, 0, stream>>>(x, label, tokseq, hbuf, barcnt);

    void* kargs[] = { (void*)&W_hh, (void*)&Gimgb, (void*)&Gtok, (void*)&W_fc,
                      (void*)&b_fc, (void*)&tokseq, (void*)&hbuf, (void*)&logits,
                      (void*)&barcnt };
    hipLaunchCooperativeKernel((void*)lstm_fused, dim3(256), dim3(1024), kargs, 0, stream);

    argmax_kernel<<<(BB * TSTEPS) / 4, 256, 0, stream>>>(logits, preds);
}